// Round 6
// baseline (466.399 us; speedup 1.0000x reference)
//
#include <hip/hip_runtime.h>

#define N_NODES 65536
#define NGROUND 32768
#define NHALF 32768
#define H 64
#define FIN 32
#define NB 64
#define MAXDEG 10
#define RSTRIDE 32769
#define EG 1048576
#define ES 1048576
#define EX 524288
#define TE (EG + EX + ES + EX)
#define BIN2 512
#define NPB 64
#define CHUNK 8192
#define TC 384
#define CNT_LEN 196608
#define NSCANB 192
#define BCAP 6144
#define NEB 2048
#define NFB 32

typedef __attribute__((ext_vector_type(8))) short short8;
typedef __attribute__((ext_vector_type(4))) float f32x4;
typedef __attribute__((ext_vector_type(2))) unsigned int u32x2;
typedef __attribute__((ext_vector_type(4))) unsigned int u32x4;
typedef unsigned short u16;
typedef unsigned int u32;

__device__ __forceinline__ u16 f2bf(float x) {
    unsigned int u = __float_as_uint(x);
    unsigned int r = u + 0x7FFFu + ((u >> 16) & 1u);
    return (u16)(r >> 16);
}
__device__ __forceinline__ float bf2f(u16 b) {
    return __uint_as_float(((unsigned int)b) << 16);
}
__device__ __forceinline__ u32 relu2(u32 w) {
    u32 lo = w & 0xFFFFu;
    if (lo & 0x8000u) lo = 0;
    u32 hi = w >> 16;
    if (hi & 0x8000u) hi = 0;
    return lo | (hi << 16);
}

__device__ __forceinline__ void chunk_resolve(int b, int& set, int& cin,
                                              int& nc, int& base, int& dbase, int& sbase) {
    if (b < 128)      { set = 0; cin = b;       nc = 128; base = 0;      dbase = 0;       sbase = 0; }
    else if (b < 192) { set = 1; cin = b - 128; nc = 64;  base = 65536;  dbase = NGROUND; sbase = 0; }
    else if (b < 320) { set = 2; cin = b - 192; nc = 128; base = 98304;  dbase = NGROUND; sbase = NGROUND; }
    else              { set = 3; cin = b - 320; nc = 64;  base = 163840; dbase = 0;       sbase = NGROUND; }
}

// Merged launch: [0,NEB) embed; [NEB,NEB+NFB) frag prep; rest: dst histogram.
__global__ __launch_bounds__(256) void embed_prep_count_kernel(
    const float* __restrict__ x, const float* __restrict__ W,
    const float* __restrict__ b, u16* __restrict__ hgHi, u16* __restrict__ hsHi,
    const float* W0l, const float* W0r, const float* W1l, const float* W1r,
    const float* W2l, const float* W2r, const float* W3l, const float* W3r,
    short8* __restrict__ fragbuf,
    const int* __restrict__ d0, const int* __restrict__ d1,
    const int* __restrict__ d2, const int* __restrict__ d3,
    int* __restrict__ cnt) {
    int tid = threadIdx.x;
    if (blockIdx.x >= NEB + NFB) {
        __shared__ int hist[BIN2];
        int set, cin, nc, base, dbase, sbase;
        chunk_resolve(blockIdx.x - NEB - NFB, set, cin, nc, base, dbase, sbase);
        const int* dp = set == 0 ? d0 : set == 1 ? d1 : set == 2 ? d2 : d3;
        for (int i = tid; i < BIN2; i += 256) hist[i] = 0;
        __syncthreads();
        int e0 = cin * CHUNK;
        for (int i = tid; i < CHUNK; i += 256) {
            int d = __builtin_nontemporal_load(&dp[e0 + i]) - dbase;
            atomicAdd(&hist[d >> 6], 1);
        }
        __syncthreads();
        for (int i = tid; i < BIN2; i += 256)
            cnt[base + i * nc + cin] = hist[i];
        return;
    }
    if (blockIdx.x >= NEB) {
        int tid2 = (blockIdx.x - NEB) * 256 + tid;
        int lane = tid2 & 63;
        int f8 = (tid2 >> 6) & 7;
        int mat = (tid2 >> 9) & 1;
        int layer = (tid2 >> 10) & 1;
        int set = (tid2 >> 11) & 3;
        int s = f8 >> 2, t = f8 & 3;
        const float* Wb;
        if (set == 0) Wb = mat ? W0r : W0l;
        else if (set == 1) Wb = mat ? W1r : W1l;
        else if (set == 2) Wb = mat ? W2r : W2l;
        else Wb = mat ? W3r : W3l;
        Wb += ((size_t)layer * (MAXDEG + 1) + MAXDEG) * H * H;
        int k0 = s * 32 + (lane >> 4) * 8;
        int n = t * 16 + (lane & 15);
        short8 hi, lo;
#pragma unroll
        for (int j = 0; j < 8; j++) {
            float w = Wb[(size_t)(k0 + j) * H + n];
            u16 hb = f2bf(w);
            u16 lb = f2bf(w - bf2f(hb));
            hi[j] = (short)hb;
            lo[j] = (short)lb;
        }
        size_t basehi = ((size_t)(((set * 2 + layer) * 2 + mat) * 2 + 0) * 8 + f8) * 64 + lane;
        size_t baselo = ((size_t)(((set * 2 + layer) * 2 + mat) * 2 + 1) * 8 + f8) * 64 + lane;
        fragbuf[basehi] = hi;
        fragbuf[baselo] = lo;
        return;
    }
    int f = tid & 63;
    int wy = tid >> 6;
    __shared__ float sW[FIN * H];
    for (int i = tid; i < FIN * H; i += 256) sW[i] = W[i];
    __syncthreads();
    float bf_ = b[f];
#pragma unroll
    for (int it = 0; it < 8; it++) {
        int node = blockIdx.x * 32 + it * 4 + wy;
        const float* xr = x + (size_t)node * FIN;
        float acc = bf_;
#pragma unroll
        for (int k = 0; k < FIN; k++) acc += xr[k] * sW[k * H + f];
        if (node < NGROUND)
            hgHi[(size_t)node * H + f] = f2bf(acc);
        else
            hsHi[(size_t)(node - NGROUND) * H + f] = f2bf(acc);
    }
}

__global__ __launch_bounds__(256) void scanA_kernel(
    int* __restrict__ cnt, int* __restrict__ bsum) {
    __shared__ int lds[256];
    int t = threadIdx.x;
    int base = blockIdx.x * 1024 + t * 4;
    int v0 = cnt[base], v1 = cnt[base + 1], v2 = cnt[base + 2], v3 = cnt[base + 3];
    int s = v0 + v1 + v2 + v3;
    lds[t] = s;
    __syncthreads();
    for (int d = 1; d < 256; d <<= 1) {
        int x = 0;
        if (t >= d) x = lds[t - d];
        __syncthreads();
        lds[t] += x;
        __syncthreads();
    }
    int pref = lds[t] - s;
    cnt[base] = pref;
    cnt[base + 1] = pref + v0;
    cnt[base + 2] = pref + v0 + v1;
    cnt[base + 3] = pref + v0 + v1 + v2;
    if (t == 255) bsum[blockIdx.x] = pref + s;
}

__global__ __launch_bounds__(256) void scanB_kernel(int* __restrict__ bsum) {
    __shared__ int lds[256];
    int t = threadIdx.x;
    int v = (t < NSCANB) ? bsum[t] : 0;
    lds[t] = v;
    __syncthreads();
    for (int d = 1; d < 256; d <<= 1) {
        int x = 0;
        if (t >= d) x = lds[t - d];
        __syncthreads();
        lds[t] += x;
        __syncthreads();
    }
    if (t < NSCANB) bsum[t] = lds[t] - v;
}

__global__ __launch_bounds__(256) void partition_kernel(
    const int* __restrict__ s0, const int* __restrict__ s1,
    const int* __restrict__ s2, const int* __restrict__ s3,
    const int* __restrict__ d0, const int* __restrict__ d1,
    const int* __restrict__ d2, const int* __restrict__ d3,
    const int* __restrict__ cnt, const int* __restrict__ bsum,
    u32* __restrict__ csru) {
    __shared__ u32 buf[CHUNK];
    __shared__ int hist[BIN2];
    __shared__ int lofs[BIN2];
    __shared__ int gbase[BIN2];
    __shared__ int sc[256];
    int set, cin, nc, base, dbase, sbase;
    chunk_resolve(blockIdx.x, set, cin, nc, base, dbase, sbase);
    const int* dp = set == 0 ? d0 : set == 1 ? d1 : set == 2 ? d2 : d3;
    const int* sp = set == 0 ? s0 : set == 1 ? s1 : set == 2 ? s2 : s3;
    int t = threadIdx.x;
    for (int i = t; i < BIN2; i += 256) hist[i] = 0;
    __syncthreads();
    u32 pk[32];
    int e0 = cin * CHUNK;
#pragma unroll
    for (int j = 0; j < 32; j++) {
        int idx = e0 + t + j * 256;
        int d = __builtin_nontemporal_load(&dp[idx]) - dbase;
        int s = __builtin_nontemporal_load(&sp[idx]) - sbase;
        pk[j] = ((u32)d << 15) | (u32)s;
        atomicAdd(&hist[d >> 6], 1);
    }
    __syncthreads();
    int h0 = hist[2 * t], h1 = hist[2 * t + 1];
    int hs = h0 + h1;
    sc[t] = hs;
    __syncthreads();
    for (int d2 = 1; d2 < 256; d2 <<= 1) {
        int v = 0;
        if (t >= d2) v = sc[t - d2];
        __syncthreads();
        sc[t] += v;
        __syncthreads();
    }
    int pref = sc[t] - hs;
    lofs[2 * t] = pref;
    lofs[2 * t + 1] = pref + h0;
    hist[2 * t] = pref;
    hist[2 * t + 1] = pref + h0;
    for (int i = t; i < BIN2; i += 256) {
        int idx = base + i * nc + cin;
        gbase[i] = cnt[idx] + bsum[idx >> 10];
    }
    __syncthreads();
#pragma unroll
    for (int j = 0; j < 32; j++) {
        int bin = pk[j] >> 21;
        int pos = atomicAdd(&hist[bin], 1);
        buf[pos] = pk[j];
    }
    __syncthreads();
    for (int i = t; i < CHUNK; i += 256) {
        u32 pkt = buf[i];
        int d = pkt >> 15;
        int bin = d >> 6;
        int gpos = gbase[bin] + (i - lofs[bin]);
        __builtin_nontemporal_store(pkt & 0x1FFFFFu, &csru[gpos]);
    }
}

__global__ __launch_bounds__(256) void finalize_kernel(
    u32* __restrict__ csru, const int* __restrict__ cnt,
    const int* __restrict__ bsum, int* __restrict__ rowstart4) {
    __shared__ u32 buf[BCAP];
    __shared__ int deg[NPB], off[NPB];
    int b = blockIdx.x;
    int set = b >> 9, bin = b & 511;
    int nc = (set == 0 || set == 2) ? 128 : 64;
    int base = set == 0 ? 0 : set == 1 ? 65536 : set == 2 ? 98304 : 163840;
    int flat = base + bin * nc;
    int binstart = cnt[flat] + bsum[flat >> 10];
    int binend = (b == 2047) ? TE : (cnt[flat + nc] + bsum[(flat + nc) >> 10]);
    int n = binend - binstart;
    for (int i = threadIdx.x; i < n; i += 256)
        buf[i] = __builtin_nontemporal_load(&csru[binstart + i]);
    if (threadIdx.x < NPB) deg[threadIdx.x] = 0;
    __syncthreads();
    for (int i = threadIdx.x; i < n; i += 256) atomicAdd(&deg[buf[i] >> 15], 1);
    __syncthreads();
    if (threadIdx.x == 0) {
        int r = 0;
        for (int j = 0; j < NPB; j++) { off[j] = r; r += deg[j]; }
    }
    __syncthreads();
    int coffset = set == 0 ? 0 : set == 1 ? EG : set == 2 ? EG + EX : EG + EX + ES;
    if (threadIdx.x < NPB)
        rowstart4[set * RSTRIDE + bin * NPB + threadIdx.x] =
            binstart - coffset + off[threadIdx.x];
    if (bin == 0 && threadIdx.x == 0)
        rowstart4[set * RSTRIDE + NHALF] = (set == 0 || set == 2) ? EG : EX;
    if (threadIdx.x < NPB) deg[threadIdx.x] = off[threadIdx.x];
    __syncthreads();
    for (int i = threadIdx.x; i < n; i += 256) {
        u32 pkt = buf[i];
        int dl = pkt >> 15;
        int pos = atomicAdd(&deg[dl], 1);
        __builtin_nontemporal_store(pkt & 0x7FFFu, &csru[binstart + pos]);
    }
}

// Fused conv: block = 4 waves = 16 nodes. h pure bf16.
// Phase 1 (MFMA-routed gather), tr_b16 staging + streaming-hint discipline:
//   read-once streams (csr, selfHi) use nontemporal loads and outHi uses
//   nontemporal stores so the per-XCD L2 keeps the randomly-gathered srcHi
//   table resident (4 MB table == 4 MB L2; stream pollution was evicting it).
// Phase 2: unchanged transform (4 MFMAs per (s,t)).
__global__ __launch_bounds__(256) void conv_fused_kernel(
    const u16* __restrict__ srcHi, const u16* __restrict__ selfHi,
    u16* __restrict__ outHi, const int* __restrict__ csr,
    const int* __restrict__ rowstart, const short8* __restrict__ fragbase,
    const float* __restrict__ Wlp, const float* __restrict__ Wrp,
    const float* __restrict__ blp, int do_relu, u32* __restrict__ relu_buf) {
    if (blockIdx.x >= 2048) {
        int base = ((blockIdx.x - 2048) * 256 + threadIdx.x) * 2;
        u32x4* p = (u32x4*)relu_buf;
        u32x4 a = __builtin_nontemporal_load(&p[base]);
        u32x4 b = __builtin_nontemporal_load(&p[base + 1]);
        a.x = relu2(a.x); a.y = relu2(a.y); a.z = relu2(a.z); a.w = relu2(a.w);
        b.x = relu2(b.x); b.y = relu2(b.y); b.z = relu2(b.z); b.w = relu2(b.w);
        __builtin_nontemporal_store(a, &p[base]);
        __builtin_nontemporal_store(b, &p[base + 1]);
        return;
    }
    __shared__ u16 sB[4][64][16];    // [wave][edge][feat-of-quarter], 8 KB
    __shared__ float sAgg[16][68];
    int tid = threadIdx.x;
    int w = tid >> 6, lane = tid & 63;
    int node0 = blockIdx.x * 16;
    int q = lane >> 4, mrow = lane & 15;

    int R0 = rowstart[node0];
    int R16 = rowstart[node0 + 16];
    int rlo = rowstart[node0 + mrow];
    int rhi = rowstart[node0 + mrow + 1];
    u32 rspan = (u32)(rhi - rlo);
    // replay-sanity clamp (no-op on real data: max block edges << 8192)
    R16 = min(max(R16, R0), R0 + 8192);

    f32x4 aggv = (f32x4){0.f, 0.f, 0.f, 0.f};

    int el = lane;            // edge slot this thread stages
    int fh = w;               // feature quarter: features fh*16 .. fh*16+15
    // LDS addresses: low 32 bits of a generic pointer to LDS == LDS byte offset
    u32 lds_rd = (u32)(uintptr_t)(&sB[w][0][0]) + (u32)lane * 8u;

    for (int ce = R0; ce < R16; ce += 64) {
        int eg = ce + el;
        int src = __builtin_nontemporal_load(&csr[min(eg, R16 - 1)]);   // clamp; A-mask zeroes overflow
        const u32x4* rp = (const u32x4*)(srcHi + (size_t)src * H + fh * 16);
        u32x4 va = rp[0];
        u32x4 vb = rp[1];
        __syncthreads();   // previous chunk fully consumed
        *(u32x4*)&sB[w][el][0] = va;
        *(u32x4*)&sB[w][el][8] = vb;
        __syncthreads();
        u32x2 r0, r1, r2, r3;
        asm volatile(
            "ds_read_b64_tr_b16 %0, %4 offset:0\n\t"
            "ds_read_b64_tr_b16 %1, %4 offset:512\n\t"
            "ds_read_b64_tr_b16 %2, %4 offset:1024\n\t"
            "ds_read_b64_tr_b16 %3, %4 offset:1536\n\t"
            "s_waitcnt lgkmcnt(0)"
            : "=&v"(r0), "=&v"(r1), "=&v"(r2), "=&v"(r3)
            : "v"(lds_rd)
            : "memory");
        __builtin_amdgcn_sched_barrier(0);
#pragma unroll
        for (int half = 0; half < 2; half++) {
            int ebase = ce + half * 32 + q * 4;
            short8 Af;
#pragma unroll
            for (int j = 0; j < 8; j++) {
                int E = ebase + ((j < 4) ? j : (12 + j));
                u32 off = (u32)E - (u32)rlo;
                Af[j] = (off < rspan) ? (short)0x3F80 : (short)0;
            }
            union { short8 s; u32 u[4]; } bb;
            if (half == 0) {
                bb.u[0] = r0[0]; bb.u[1] = r0[1];
                bb.u[2] = r1[0]; bb.u[3] = r1[1];
            } else {
                bb.u[0] = r2[0]; bb.u[1] = r2[1];
                bb.u[2] = r3[0]; bb.u[3] = r3[1];
            }
            aggv = __builtin_amdgcn_mfma_f32_16x16x32_bf16(Af, bb.s, aggv, 0, 0, 0);
        }
    }
    // C layout: row m = q*4+r, col n = w*16 + mrow
#pragma unroll
    for (int r = 0; r < 4; r++) sAgg[q * 4 + r][w * 16 + mrow] = aggv[r];
    __syncthreads();

    // ---- phase 2: transform (wave w owns t-tile t = w) ----
    int myrow = node0 + mrow;
    int mydeg = rhi - rlo;
    unsigned long long ball = __ballot(min(mydeg, MAXDEG) != MAXDEG);
    unsigned exc = (unsigned)(ball & 0xFFFFull);
    int t = w;

    f32x4 accv = (f32x4){0.f, 0.f, 0.f, 0.f};
    const short8* fb = fragbase + lane;
#pragma unroll
    for (int s = 0; s < 2; s++) {
        float av[8];
        *(float4*)&av[0] = *(const float4*)&sAgg[mrow][s * 32 + q * 8];
        *(float4*)&av[4] = *(const float4*)&sAgg[mrow][s * 32 + q * 8 + 4];
        short8 Ahi;
#pragma unroll
        for (int j = 0; j < 8; j++) Ahi[j] = (short)f2bf(av[j]);
        union { u32x4 u; short8 s; } hh;
        hh.u = __builtin_nontemporal_load(
            (const u32x4*)(selfHi + (size_t)myrow * H + s * 32 + q * 8));
        short8 Hhi = hh.s;
        short8 BLhi = fb[(size_t)((0 * 8) + s * 4 + t) * 64];
        short8 BLlo = fb[(size_t)((1 * 8) + s * 4 + t) * 64];
        short8 BRhi = fb[(size_t)((2 * 8) + s * 4 + t) * 64];
        short8 BRlo = fb[(size_t)((3 * 8) + s * 4 + t) * 64];
        accv = __builtin_amdgcn_mfma_f32_16x16x32_bf16(Ahi, BLhi, accv, 0, 0, 0);
        accv = __builtin_amdgcn_mfma_f32_16x16x32_bf16(Ahi, BLlo, accv, 0, 0, 0);
        accv = __builtin_amdgcn_mfma_f32_16x16x32_bf16(Hhi, BRhi, accv, 0, 0, 0);
        accv = __builtin_amdgcn_mfma_f32_16x16x32_bf16(Hhi, BRlo, accv, 0, 0, 0);
    }

    {
        int n = t * 16 + mrow;
        float bv = blp[MAXDEG * H + n];
#pragma unroll
        for (int r = 0; r < 4; r++) {
            int mm = q * 4 + r;
            if (!((exc >> mm) & 1)) {
                float val = accv[r] + bv;
                if (do_relu) val = fmaxf(val, 0.f);
                __builtin_nontemporal_store(f2bf(val), &outHi[(size_t)(node0 + mm) * H + n]);
            }
        }
    }

    // ---- exact fp32 fallback: wave w covers nodes w*4..w*4+3 ----
    if (exc & (0xFu << (w * 4))) {
        for (int i = 0; i < 4; i++) {
            int nr = w * 4 + i;
            if (!((exc >> nr) & 1)) continue;
            int node = node0 + nr;
            int st = rowstart[node], en = rowstart[node + 1];
            int dg = en - st;
            if (dg == 0) {
                float v = bf2f(selfHi[(size_t)node * H + lane]);
                if (do_relu) v = fmaxf(v, 0.f);
                __builtin_nontemporal_store(f2bf(v), &outHi[(size_t)node * H + lane]);
            } else {
                int d = min(dg, MAXDEG);
                const float* wl = Wlp + (size_t)d * H * H;
                const float* wr = Wrp + (size_t)d * H * H;
                float sval = bf2f(selfHi[(size_t)node * H + lane]);
                float o = blp[d * H + lane];
#pragma unroll 4
                for (int k = 0; k < H; k++) {
                    o += sAgg[nr][k] * wl[k * H + lane];
                    o += __shfl(sval, k, 64) * wr[k * H + lane];
                }
                if (do_relu) o = fmaxf(o, 0.f);
                __builtin_nontemporal_store(f2bf(o), &outHi[(size_t)node * H + lane]);
            }
        }
    }
}

__global__ __launch_bounds__(256) void pool_kernel(
    const u16* __restrict__ hgHi, const int* __restrict__ batch_idx,
    float* __restrict__ pooled) {
    __shared__ float lp[NB * H];
    int tid = threadIdx.x;
    for (int i = tid; i < NB * H; i += 256) lp[i] = 0.f;
    __syncthreads();
    int f = tid & 63;
    int wave = tid >> 6;
    int start = blockIdx.x * 64;
    for (int n = wave; n < 64; n += 4) {
        int node = start + n;
        int bi = batch_idx[node];
        atomicAdd(&lp[bi * H + f], bf2f(__builtin_nontemporal_load(&hgHi[(size_t)node * H + f])));
    }
    __syncthreads();
    for (int i = tid; i < NB * H; i += 256) {
        float v = lp[i];
        if (v != 0.f) atomicAdd(&pooled[i], v);
    }
}

__global__ __launch_bounds__(64) void mlp_kernel(
    const float* __restrict__ pooled, const float* __restrict__ W1,
    const float* __restrict__ b1, const float* __restrict__ W2,
    const float* __restrict__ b2, float* __restrict__ out) {
    int b = blockIdx.x;
    int j = threadIdx.x;
    const float* pr = pooled + b * H;
    float acc = b1[j];
#pragma unroll
    for (int k = 0; k < H; k++) acc += pr[k] * W1[k * H + j];
    acc = fmaxf(acc, 0.f);
    float v = acc * W2[j];
#pragma unroll
    for (int off = 32; off > 0; off >>= 1) v += __shfl_down(v, off, 64);
    if (j == 0) out[b] = v + b2[0];
}

extern "C" void kernel_launch(void* const* d_in, const int* in_sizes, int n_in,
                              void* d_out, int out_size, void* d_ws, size_t ws_size,
                              hipStream_t stream) {
    const float* x = (const float*)d_in[0];
    const int* ei_ground = (const int*)d_in[1];
    const int* ei_sub = (const int*)d_in[2];
    const int* ei_g2s = (const int*)d_in[3];
    const int* ei_s2g = (const int*)d_in[4];
    const int* batch_idx = (const int*)d_in[7];
    const float* embed_W = (const float*)d_in[8];
    const float* embed_b = (const float*)d_in[9];
    const float* Wl[4] = {(const float*)d_in[10], (const float*)d_in[13],
                          (const float*)d_in[16], (const float*)d_in[19]};
    const float* bl[4] = {(const float*)d_in[11], (const float*)d_in[14],
                          (const float*)d_in[17], (const float*)d_in[20]};
    const float* Wr[4] = {(const float*)d_in[12], (const float*)d_in[15],
                          (const float*)d_in[18], (const float*)d_in[21]};
    const float* W1 = (const float*)d_in[22];
    const float* b1 = (const float*)d_in[23];
    const float* W2 = (const float*)d_in[24];
    const float* b2 = (const float*)d_in[25];

    const int* s_[4] = {ei_ground, ei_g2s, ei_sub, ei_s2g};
    const int* dsr[4] = {ei_ground + EG, ei_g2s + EX, ei_sub + ES, ei_s2g + EX};
    const size_t coff[4] = {0, (size_t)EG, (size_t)EG + EX, (size_t)EG + EX + ES};

    const size_t HB = (size_t)NHALF * H * sizeof(u16);
    char* p = (char*)d_ws;
    u16* hgHi[2] = {(u16*)p, (u16*)(p + HB)};            p += 2 * HB;
    u16* hsHi[2] = {(u16*)p, (u16*)(p + HB)};            p += 2 * HB;
    u32* csru = (u32*)p;           p += (size_t)TE * sizeof(u32);
    int* cnt = (int*)p;            p += (size_t)CNT_LEN * sizeof(int);
    int* bsum = (int*)p;           p += (size_t)NSCANB * sizeof(int);
    int* rowstart4 = (int*)p;      p += (size_t)4 * RSTRIDE * sizeof(int);
    p += 16 - ((size_t)p & 15);
    short8* fragbuf = (short8*)p;  p += (size_t)8192 * sizeof(short8);
    float* pooled = (float*)p;

    // ---- merged: embed + weight-fragment prep + dst histogram ----
    embed_prep_count_kernel<<<NEB + NFB + TC, 256, 0, stream>>>(
        x, embed_W, embed_b, hgHi[0], hsHi[0],
        Wl[0], Wr[0], Wl[1], Wr[1], Wl[2], Wr[2], Wl[3], Wr[3], fragbuf,
        dsr[0], dsr[1], dsr[2], dsr[3], cnt);

    // ---- CSR build ----
    scanA_kernel<<<NSCANB, 256, 0, stream>>>(cnt, bsum);
    scanB_kernel<<<1, 256, 0, stream>>>(bsum);
    partition_kernel<<<TC, 256, 0, stream>>>(
        s_[0], s_[1], s_[2], s_[3], dsr[0], dsr[1], dsr[2], dsr[3], cnt, bsum, csru);
    finalize_kernel<<<2048, 256, 0, stream>>>(csru, cnt, bsum, rowstart4);
    const int* csr = (const int*)csru;

    // ---- conv layers ----
    int cg = 0, cs = 0;
    for (int l = 0; l < 2; l++) {
        for (int c = 0; c < 4; c++) {
            const u16 *srcHi, *selfHi;
            u16 *outHi;
            if (c == 0)      { srcHi = hgHi[cg]; selfHi = hgHi[cg]; outHi = hgHi[1 - cg]; }
            else if (c == 1) { srcHi = hgHi[cg]; selfHi = hsHi[cs]; outHi = hsHi[1 - cs]; }
            else if (c == 2) { srcHi = hsHi[cs]; selfHi = hsHi[cs]; outHi = hsHi[1 - cs]; }
            else             { srcHi = hsHi[cs]; selfHi = hgHi[cg]; outHi = hgHi[1 - cg]; }
            int do_relu = (l == 0 && c == 3) ? 1 : 0;
            int relu_blocks = (l == 1 && c == 0) ? 512 : 0;
            u32* relu_buf = (l == 1 && c == 0) ? (u32*)hsHi[cs] : (u32*)nullptr;
            conv_fused_kernel<<<2048 + relu_blocks, 256, 0, stream>>>(
                srcHi, selfHi, outHi,
                csr + coff[c], rowstart4 + (size_t)c * RSTRIDE,
                fragbuf + (size_t)(c * 2 + l) * 2048,
                Wl[c] + (size_t)l * (MAXDEG + 1) * H * H,
                Wr[c] + (size_t)l * (MAXDEG + 1) * H * H,
                bl[c] + (size_t)l * (MAXDEG + 1) * H, do_relu, relu_buf);
            if (c == 0 || c == 3) cg ^= 1; else cs ^= 1;
        }
    }

    // ---- pool + MLP ----
    hipMemsetAsync(pooled, 0, (size_t)NB * H * sizeof(float), stream);
    pool_kernel<<<NGROUND / 64, 256, 0, stream>>>(hgHi[cg], batch_idx, pooled);
    mlp_kernel<<<NB, 64, 0, stream>>>(pooled, W1, b1, W2, b2, (float*)d_out);
}

// Round 7
// 375.135 us; speedup vs baseline: 1.2433x; 1.2433x over previous
//
#include <hip/hip_runtime.h>

#define N_NODES 65536
#define NGROUND 32768
#define NHALF 32768
#define H 64
#define FIN 32
#define NB 64
#define MAXDEG 10
#define RSTRIDE 32769
#define EG 1048576
#define ES 1048576
#define EX 524288
#define TE (EG + EX + ES + EX)
#define BIN2 512
#define NPB 64
#define CHUNK 8192
#define TC 384
#define CNT_LEN 196608
#define NSCANB 192
#define BCAP 6144
#define NEB 2048
#define NFB 32

typedef __attribute__((ext_vector_type(8))) short short8;
typedef __attribute__((ext_vector_type(4))) float f32x4;
typedef __attribute__((ext_vector_type(2))) unsigned int u32x2;
typedef __attribute__((ext_vector_type(4))) unsigned int u32x4;
typedef unsigned short u16;
typedef unsigned int u32;

__device__ __forceinline__ u16 f2bf(float x) {
    unsigned int u = __float_as_uint(x);
    unsigned int r = u + 0x7FFFu + ((u >> 16) & 1u);
    return (u16)(r >> 16);
}
__device__ __forceinline__ float bf2f(u16 b) {
    return __uint_as_float(((unsigned int)b) << 16);
}
__device__ __forceinline__ u32 relu2(u32 w) {
    u32 lo = w & 0xFFFFu;
    if (lo & 0x8000u) lo = 0;
    u32 hi = w >> 16;
    if (hi & 0x8000u) hi = 0;
    return lo | (hi << 16);
}

__device__ __forceinline__ void chunk_resolve(int b, int& set, int& cin,
                                              int& nc, int& base, int& dbase, int& sbase) {
    if (b < 128)      { set = 0; cin = b;       nc = 128; base = 0;      dbase = 0;       sbase = 0; }
    else if (b < 192) { set = 1; cin = b - 128; nc = 64;  base = 65536;  dbase = NGROUND; sbase = 0; }
    else if (b < 320) { set = 2; cin = b - 192; nc = 128; base = 98304;  dbase = NGROUND; sbase = NGROUND; }
    else              { set = 3; cin = b - 320; nc = 64;  base = 163840; dbase = 0;       sbase = NGROUND; }
}

// Merged launch: [0,NEB) embed; [NEB,NEB+NFB) frag prep; rest: dst histogram.
__global__ __launch_bounds__(256) void embed_prep_count_kernel(
    const float* __restrict__ x, const float* __restrict__ W,
    const float* __restrict__ b, u16* __restrict__ hgHi, u16* __restrict__ hsHi,
    const float* W0l, const float* W0r, const float* W1l, const float* W1r,
    const float* W2l, const float* W2r, const float* W3l, const float* W3r,
    short8* __restrict__ fragbuf,
    const int* __restrict__ d0, const int* __restrict__ d1,
    const int* __restrict__ d2, const int* __restrict__ d3,
    int* __restrict__ cnt) {
    int tid = threadIdx.x;
    if (blockIdx.x >= NEB + NFB) {
        __shared__ int hist[BIN2];
        int set, cin, nc, base, dbase, sbase;
        chunk_resolve(blockIdx.x - NEB - NFB, set, cin, nc, base, dbase, sbase);
        const int* dp = set == 0 ? d0 : set == 1 ? d1 : set == 2 ? d2 : d3;
        for (int i = tid; i < BIN2; i += 256) hist[i] = 0;
        __syncthreads();
        int e0 = cin * CHUNK;
        for (int i = tid; i < CHUNK; i += 256) {
            int d = __builtin_nontemporal_load(&dp[e0 + i]) - dbase;
            atomicAdd(&hist[d >> 6], 1);
        }
        __syncthreads();
        for (int i = tid; i < BIN2; i += 256)
            cnt[base + i * nc + cin] = hist[i];
        return;
    }
    if (blockIdx.x >= NEB) {
        int tid2 = (blockIdx.x - NEB) * 256 + tid;
        int lane = tid2 & 63;
        int f8 = (tid2 >> 6) & 7;
        int mat = (tid2 >> 9) & 1;
        int layer = (tid2 >> 10) & 1;
        int set = (tid2 >> 11) & 3;
        int s = f8 >> 2, t = f8 & 3;
        const float* Wb;
        if (set == 0) Wb = mat ? W0r : W0l;
        else if (set == 1) Wb = mat ? W1r : W1l;
        else if (set == 2) Wb = mat ? W2r : W2l;
        else Wb = mat ? W3r : W3l;
        Wb += ((size_t)layer * (MAXDEG + 1) + MAXDEG) * H * H;
        int k0 = s * 32 + (lane >> 4) * 8;
        int n = t * 16 + (lane & 15);
        short8 hi, lo;
#pragma unroll
        for (int j = 0; j < 8; j++) {
            float w = Wb[(size_t)(k0 + j) * H + n];
            u16 hb = f2bf(w);
            u16 lb = f2bf(w - bf2f(hb));
            hi[j] = (short)hb;
            lo[j] = (short)lb;
        }
        size_t basehi = ((size_t)(((set * 2 + layer) * 2 + mat) * 2 + 0) * 8 + f8) * 64 + lane;
        size_t baselo = ((size_t)(((set * 2 + layer) * 2 + mat) * 2 + 1) * 8 + f8) * 64 + lane;
        fragbuf[basehi] = hi;
        fragbuf[baselo] = lo;
        return;
    }
    int f = tid & 63;
    int wy = tid >> 6;
    __shared__ float sW[FIN * H];
    for (int i = tid; i < FIN * H; i += 256) sW[i] = W[i];
    __syncthreads();
    float bf_ = b[f];
#pragma unroll
    for (int it = 0; it < 8; it++) {
        int node = blockIdx.x * 32 + it * 4 + wy;
        const float* xr = x + (size_t)node * FIN;
        float acc = bf_;
#pragma unroll
        for (int k = 0; k < FIN; k++) acc += xr[k] * sW[k * H + f];
        if (node < NGROUND)
            hgHi[(size_t)node * H + f] = f2bf(acc);
        else
            hsHi[(size_t)(node - NGROUND) * H + f] = f2bf(acc);
    }
}

__global__ __launch_bounds__(256) void scanA_kernel(
    int* __restrict__ cnt, int* __restrict__ bsum) {
    __shared__ int lds[256];
    int t = threadIdx.x;
    int base = blockIdx.x * 1024 + t * 4;
    int v0 = cnt[base], v1 = cnt[base + 1], v2 = cnt[base + 2], v3 = cnt[base + 3];
    int s = v0 + v1 + v2 + v3;
    lds[t] = s;
    __syncthreads();
    for (int d = 1; d < 256; d <<= 1) {
        int x = 0;
        if (t >= d) x = lds[t - d];
        __syncthreads();
        lds[t] += x;
        __syncthreads();
    }
    int pref = lds[t] - s;
    cnt[base] = pref;
    cnt[base + 1] = pref + v0;
    cnt[base + 2] = pref + v0 + v1;
    cnt[base + 3] = pref + v0 + v1 + v2;
    if (t == 255) bsum[blockIdx.x] = pref + s;
}

__global__ __launch_bounds__(256) void scanB_kernel(int* __restrict__ bsum) {
    __shared__ int lds[256];
    int t = threadIdx.x;
    int v = (t < NSCANB) ? bsum[t] : 0;
    lds[t] = v;
    __syncthreads();
    for (int d = 1; d < 256; d <<= 1) {
        int x = 0;
        if (t >= d) x = lds[t - d];
        __syncthreads();
        lds[t] += x;
        __syncthreads();
    }
    if (t < NSCANB) bsum[t] = lds[t] - v;
}

__global__ __launch_bounds__(256) void partition_kernel(
    const int* __restrict__ s0, const int* __restrict__ s1,
    const int* __restrict__ s2, const int* __restrict__ s3,
    const int* __restrict__ d0, const int* __restrict__ d1,
    const int* __restrict__ d2, const int* __restrict__ d3,
    const int* __restrict__ cnt, const int* __restrict__ bsum,
    u32* __restrict__ csru) {
    __shared__ u32 buf[CHUNK];
    __shared__ int hist[BIN2];
    __shared__ int lofs[BIN2];
    __shared__ int gbase[BIN2];
    __shared__ int sc[256];
    int set, cin, nc, base, dbase, sbase;
    chunk_resolve(blockIdx.x, set, cin, nc, base, dbase, sbase);
    const int* dp = set == 0 ? d0 : set == 1 ? d1 : set == 2 ? d2 : d3;
    const int* sp = set == 0 ? s0 : set == 1 ? s1 : set == 2 ? s2 : s3;
    int t = threadIdx.x;
    for (int i = t; i < BIN2; i += 256) hist[i] = 0;
    __syncthreads();
    u32 pk[32];
    int e0 = cin * CHUNK;
#pragma unroll
    for (int j = 0; j < 32; j++) {
        int idx = e0 + t + j * 256;
        int d = __builtin_nontemporal_load(&dp[idx]) - dbase;
        int s = __builtin_nontemporal_load(&sp[idx]) - sbase;
        pk[j] = ((u32)d << 15) | (u32)s;
        atomicAdd(&hist[d >> 6], 1);
    }
    __syncthreads();
    int h0 = hist[2 * t], h1 = hist[2 * t + 1];
    int hs = h0 + h1;
    sc[t] = hs;
    __syncthreads();
    for (int d2 = 1; d2 < 256; d2 <<= 1) {
        int v = 0;
        if (t >= d2) v = sc[t - d2];
        __syncthreads();
        sc[t] += v;
        __syncthreads();
    }
    int pref = sc[t] - hs;
    lofs[2 * t] = pref;
    lofs[2 * t + 1] = pref + h0;
    hist[2 * t] = pref;
    hist[2 * t + 1] = pref + h0;
    for (int i = t; i < BIN2; i += 256) {
        int idx = base + i * nc + cin;
        gbase[i] = cnt[idx] + bsum[idx >> 10];
    }
    __syncthreads();
#pragma unroll
    for (int j = 0; j < 32; j++) {
        int bin = pk[j] >> 21;
        int pos = atomicAdd(&hist[bin], 1);
        buf[pos] = pk[j];
    }
    __syncthreads();
    for (int i = t; i < CHUNK; i += 256) {
        u32 pkt = buf[i];
        int d = pkt >> 15;
        int bin = d >> 6;
        int gpos = gbase[bin] + (i - lofs[bin]);
        csru[gpos] = pkt & 0x1FFFFFu;
    }
}

__global__ __launch_bounds__(256) void finalize_kernel(
    u32* __restrict__ csru, const int* __restrict__ cnt,
    const int* __restrict__ bsum, int* __restrict__ rowstart4) {
    __shared__ u32 buf[BCAP];
    __shared__ int deg[NPB], off[NPB];
    int b = blockIdx.x;
    int set = b >> 9, bin = b & 511;
    int nc = (set == 0 || set == 2) ? 128 : 64;
    int base = set == 0 ? 0 : set == 1 ? 65536 : set == 2 ? 98304 : 163840;
    int flat = base + bin * nc;
    int binstart = cnt[flat] + bsum[flat >> 10];
    int binend = (b == 2047) ? TE : (cnt[flat + nc] + bsum[(flat + nc) >> 10]);
    int n = binend - binstart;
    for (int i = threadIdx.x; i < n; i += 256) buf[i] = csru[binstart + i];
    if (threadIdx.x < NPB) deg[threadIdx.x] = 0;
    __syncthreads();
    for (int i = threadIdx.x; i < n; i += 256) atomicAdd(&deg[buf[i] >> 15], 1);
    __syncthreads();
    if (threadIdx.x == 0) {
        int r = 0;
        for (int j = 0; j < NPB; j++) { off[j] = r; r += deg[j]; }
    }
    __syncthreads();
    int coffset = set == 0 ? 0 : set == 1 ? EG : set == 2 ? EG + EX : EG + EX + ES;
    if (threadIdx.x < NPB)
        rowstart4[set * RSTRIDE + bin * NPB + threadIdx.x] =
            binstart - coffset + off[threadIdx.x];
    if (bin == 0 && threadIdx.x == 0)
        rowstart4[set * RSTRIDE + NHALF] = (set == 0 || set == 2) ? EG : EX;
    if (threadIdx.x < NPB) deg[threadIdx.x] = off[threadIdx.x];
    __syncthreads();
    for (int i = threadIdx.x; i < n; i += 256) {
        u32 pkt = buf[i];
        int dl = pkt >> 15;
        int pos = atomicAdd(&deg[dl], 1);
        csru[binstart + pos] = pkt & 0x7FFFu;
    }
}

// Fused conv: block = 4 waves = 16 nodes. h pure bf16.
// Phase 1 (MFMA-routed gather), COALESCED full-row staging + tr_b16 read:
//   wave w stages edges w*16..w*16+15 as complete 128-B rows: lane
//   (p = l&7, e = w*16 + (l>>3)) loads the p-th 16-B piece of edge e's row —
//   8 consecutive lanes cover one cache line, so each gather instruction
//   touches 8 distinct lines instead of 64 (8x fewer L1/L2 transactions,
//   same bytes). Lane writes its piece to sB[p>>1][e][(p&1)*8]; the LDS
//   image is identical to the verified R4 layout, so the tr_read + one-hot
//   routing MFMA consume phase is unchanged.
// Phase 2: unchanged transform (4 MFMAs per (s,t)).
__global__ __launch_bounds__(256) void conv_fused_kernel(
    const u16* __restrict__ srcHi, const u16* __restrict__ selfHi,
    u16* __restrict__ outHi, const int* __restrict__ csr,
    const int* __restrict__ rowstart, const short8* __restrict__ fragbase,
    const float* __restrict__ Wlp, const float* __restrict__ Wrp,
    const float* __restrict__ blp, int do_relu, u32* __restrict__ relu_buf) {
    if (blockIdx.x >= 2048) {
        int base = ((blockIdx.x - 2048) * 256 + threadIdx.x) * 2;
        u32x4* p = (u32x4*)relu_buf;
        u32x4 a = p[base], b = p[base + 1];
        a.x = relu2(a.x); a.y = relu2(a.y); a.z = relu2(a.z); a.w = relu2(a.w);
        b.x = relu2(b.x); b.y = relu2(b.y); b.z = relu2(b.z); b.w = relu2(b.w);
        p[base] = a;
        p[base + 1] = b;
        return;
    }
    __shared__ u16 sB[4][64][16];    // [quarter][edge][feat-of-quarter], 8 KB
    __shared__ float sAgg[16][68];
    int tid = threadIdx.x;
    int w = tid >> 6, lane = tid & 63;
    int node0 = blockIdx.x * 16;
    int q = lane >> 4, mrow = lane & 15;

    int R0 = rowstart[node0];
    int R16 = rowstart[node0 + 16];
    int rlo = rowstart[node0 + mrow];
    int rhi = rowstart[node0 + mrow + 1];
    u32 rspan = (u32)(rhi - rlo);
    // replay-sanity clamp (no-op on real data: max block edges << 8192)
    R16 = min(max(R16, R0), R0 + 8192);

    f32x4 aggv = (f32x4){0.f, 0.f, 0.f, 0.f};

    int p_ = lane & 7;         // 16-B piece within the 128-B row
    int e0 = w * 16 + (lane >> 3);   // first edge this lane stages
    int e1 = e0 + 8;                 // second edge
    // LDS addresses: low 32 bits of a generic pointer to LDS == LDS byte offset
    u32 lds_rd = (u32)(uintptr_t)(&sB[w][0][0]) + (u32)lane * 8u;

    for (int ce = R0; ce < R16; ce += 64) {
        int s0 = csr[min(ce + e0, R16 - 1)];   // clamp; A-mask zeroes overflow
        int s1 = csr[min(ce + e1, R16 - 1)];
        u32x4 va = *((const u32x4*)(srcHi + (size_t)s0 * H) + p_);
        u32x4 vb = *((const u32x4*)(srcHi + (size_t)s1 * H) + p_);
        __syncthreads();   // previous chunk fully consumed
        *(u32x4*)&sB[p_ >> 1][e0][(p_ & 1) * 8] = va;
        *(u32x4*)&sB[p_ >> 1][e1][(p_ & 1) * 8] = vb;
        __syncthreads();
        u32x2 r0, r1, r2, r3;
        asm volatile(
            "ds_read_b64_tr_b16 %0, %4 offset:0\n\t"
            "ds_read_b64_tr_b16 %1, %4 offset:512\n\t"
            "ds_read_b64_tr_b16 %2, %4 offset:1024\n\t"
            "ds_read_b64_tr_b16 %3, %4 offset:1536\n\t"
            "s_waitcnt lgkmcnt(0)"
            : "=&v"(r0), "=&v"(r1), "=&v"(r2), "=&v"(r3)
            : "v"(lds_rd)
            : "memory");
        __builtin_amdgcn_sched_barrier(0);
#pragma unroll
        for (int half = 0; half < 2; half++) {
            int ebase = ce + half * 32 + q * 4;
            short8 Af;
#pragma unroll
            for (int j = 0; j < 8; j++) {
                int E = ebase + ((j < 4) ? j : (12 + j));
                u32 off = (u32)E - (u32)rlo;
                Af[j] = (off < rspan) ? (short)0x3F80 : (short)0;
            }
            union { short8 s; u32 u[4]; } bb;
            if (half == 0) {
                bb.u[0] = r0[0]; bb.u[1] = r0[1];
                bb.u[2] = r1[0]; bb.u[3] = r1[1];
            } else {
                bb.u[0] = r2[0]; bb.u[1] = r2[1];
                bb.u[2] = r3[0]; bb.u[3] = r3[1];
            }
            aggv = __builtin_amdgcn_mfma_f32_16x16x32_bf16(Af, bb.s, aggv, 0, 0, 0);
        }
    }
    // C layout: row m = q*4+r, col n = w*16 + mrow
#pragma unroll
    for (int r = 0; r < 4; r++) sAgg[q * 4 + r][w * 16 + mrow] = aggv[r];
    __syncthreads();

    // ---- phase 2: transform (wave w owns t-tile t = w) ----
    int myrow = node0 + mrow;
    int mydeg = rhi - rlo;
    unsigned long long ball = __ballot(min(mydeg, MAXDEG) != MAXDEG);
    unsigned exc = (unsigned)(ball & 0xFFFFull);
    int t = w;

    f32x4 accv = (f32x4){0.f, 0.f, 0.f, 0.f};
    const short8* fb = fragbase + lane;
#pragma unroll
    for (int s = 0; s < 2; s++) {
        float av[8];
        *(float4*)&av[0] = *(const float4*)&sAgg[mrow][s * 32 + q * 8];
        *(float4*)&av[4] = *(const float4*)&sAgg[mrow][s * 32 + q * 8 + 4];
        short8 Ahi;
#pragma unroll
        for (int j = 0; j < 8; j++) Ahi[j] = (short)f2bf(av[j]);
        short8 Hhi = *(const short8*)(selfHi + (size_t)myrow * H + s * 32 + q * 8);
        short8 BLhi = fb[(size_t)((0 * 8) + s * 4 + t) * 64];
        short8 BLlo = fb[(size_t)((1 * 8) + s * 4 + t) * 64];
        short8 BRhi = fb[(size_t)((2 * 8) + s * 4 + t) * 64];
        short8 BRlo = fb[(size_t)((3 * 8) + s * 4 + t) * 64];
        accv = __builtin_amdgcn_mfma_f32_16x16x32_bf16(Ahi, BLhi, accv, 0, 0, 0);
        accv = __builtin_amdgcn_mfma_f32_16x16x32_bf16(Ahi, BLlo, accv, 0, 0, 0);
        accv = __builtin_amdgcn_mfma_f32_16x16x32_bf16(Hhi, BRhi, accv, 0, 0, 0);
        accv = __builtin_amdgcn_mfma_f32_16x16x32_bf16(Hhi, BRlo, accv, 0, 0, 0);
    }

    {
        int n = t * 16 + mrow;
        float bv = blp[MAXDEG * H + n];
#pragma unroll
        for (int r = 0; r < 4; r++) {
            int mm = q * 4 + r;
            if (!((exc >> mm) & 1)) {
                float val = accv[r] + bv;
                if (do_relu) val = fmaxf(val, 0.f);
                outHi[(size_t)(node0 + mm) * H + n] = f2bf(val);
            }
        }
    }

    // ---- exact fp32 fallback: wave w covers nodes w*4..w*4+3 ----
    if (exc & (0xFu << (w * 4))) {
        for (int i = 0; i < 4; i++) {
            int nr = w * 4 + i;
            if (!((exc >> nr) & 1)) continue;
            int node = node0 + nr;
            int st = rowstart[node], en = rowstart[node + 1];
            int dg = en - st;
            if (dg == 0) {
                float v = bf2f(selfHi[(size_t)node * H + lane]);
                if (do_relu) v = fmaxf(v, 0.f);
                outHi[(size_t)node * H + lane] = f2bf(v);
            } else {
                int d = min(dg, MAXDEG);
                const float* wl = Wlp + (size_t)d * H * H;
                const float* wr = Wrp + (size_t)d * H * H;
                float sval = bf2f(selfHi[(size_t)node * H + lane]);
                float o = blp[d * H + lane];
#pragma unroll 4
                for (int k = 0; k < H; k++) {
                    o += sAgg[nr][k] * wl[k * H + lane];
                    o += __shfl(sval, k, 64) * wr[k * H + lane];
                }
                if (do_relu) o = fmaxf(o, 0.f);
                outHi[(size_t)node * H + lane] = f2bf(o);
            }
        }
    }
}

__global__ __launch_bounds__(256) void pool_kernel(
    const u16* __restrict__ hgHi, const int* __restrict__ batch_idx,
    float* __restrict__ pooled) {
    __shared__ float lp[NB * H];
    int tid = threadIdx.x;
    for (int i = tid; i < NB * H; i += 256) lp[i] = 0.f;
    __syncthreads();
    int f = tid & 63;
    int wave = tid >> 6;
    int start = blockIdx.x * 64;
    for (int n = wave; n < 64; n += 4) {
        int node = start + n;
        int bi = batch_idx[node];
        atomicAdd(&lp[bi * H + f], bf2f(hgHi[(size_t)node * H + f]));
    }
    __syncthreads();
    for (int i = tid; i < NB * H; i += 256) {
        float v = lp[i];
        if (v != 0.f) atomicAdd(&pooled[i], v);
    }
}

__global__ __launch_bounds__(64) void mlp_kernel(
    const float* __restrict__ pooled, const float* __restrict__ W1,
    const float* __restrict__ b1, const float* __restrict__ W2,
    const float* __restrict__ b2, float* __restrict__ out) {
    int b = blockIdx.x;
    int j = threadIdx.x;
    const float* pr = pooled + b * H;
    float acc = b1[j];
#pragma unroll
    for (int k = 0; k < H; k++) acc += pr[k] * W1[k * H + j];
    acc = fmaxf(acc, 0.f);
    float v = acc * W2[j];
#pragma unroll
    for (int off = 32; off > 0; off >>= 1) v += __shfl_down(v, off, 64);
    if (j == 0) out[b] = v + b2[0];
}

extern "C" void kernel_launch(void* const* d_in, const int* in_sizes, int n_in,
                              void* d_out, int out_size, void* d_ws, size_t ws_size,
                              hipStream_t stream) {
    const float* x = (const float*)d_in[0];
    const int* ei_ground = (const int*)d_in[1];
    const int* ei_sub = (const int*)d_in[2];
    const int* ei_g2s = (const int*)d_in[3];
    const int* ei_s2g = (const int*)d_in[4];
    const int* batch_idx = (const int*)d_in[7];
    const float* embed_W = (const float*)d_in[8];
    const float* embed_b = (const float*)d_in[9];
    const float* Wl[4] = {(const float*)d_in[10], (const float*)d_in[13],
                          (const float*)d_in[16], (const float*)d_in[19]};
    const float* bl[4] = {(const float*)d_in[11], (const float*)d_in[14],
                          (const float*)d_in[17], (const float*)d_in[20]};
    const float* Wr[4] = {(const float*)d_in[12], (const float*)d_in[15],
                          (const float*)d_in[18], (const float*)d_in[21]};
    const float* W1 = (const float*)d_in[22];
    const float* b1 = (const float*)d_in[23];
    const float* W2 = (const float*)d_in[24];
    const float* b2 = (const float*)d_in[25];

    const int* s_[4] = {ei_ground, ei_g2s, ei_sub, ei_s2g};
    const int* dsr[4] = {ei_ground + EG, ei_g2s + EX, ei_sub + ES, ei_s2g + EX};
    const size_t coff[4] = {0, (size_t)EG, (size_t)EG + EX, (size_t)EG + EX + ES};

    const size_t HB = (size_t)NHALF * H * sizeof(u16);
    char* p = (char*)d_ws;
    u16* hgHi[2] = {(u16*)p, (u16*)(p + HB)};            p += 2 * HB;
    u16* hsHi[2] = {(u16*)p, (u16*)(p + HB)};            p += 2 * HB;
    u32* csru = (u32*)p;           p += (size_t)TE * sizeof(u32);
    int* cnt = (int*)p;            p += (size_t)CNT_LEN * sizeof(int);
    int* bsum = (int*)p;           p += (size_t)NSCANB * sizeof(int);
    int* rowstart4 = (int*)p;      p += (size_t)4 * RSTRIDE * sizeof(int);
    p += 16 - ((size_t)p & 15);
    short8* fragbuf = (short8*)p;  p += (size_t)8192 * sizeof(short8);
    float* pooled = (float*)p;

    // ---- merged: embed + weight-fragment prep + dst histogram ----
    embed_prep_count_kernel<<<NEB + NFB + TC, 256, 0, stream>>>(
        x, embed_W, embed_b, hgHi[0], hsHi[0],
        Wl[0], Wr[0], Wl[1], Wr[1], Wl[2], Wr[2], Wl[3], Wr[3], fragbuf,
        dsr[0], dsr[1], dsr[2], dsr[3], cnt);

    // ---- CSR build ----
    scanA_kernel<<<NSCANB, 256, 0, stream>>>(cnt, bsum);
    scanB_kernel<<<1, 256, 0, stream>>>(bsum);
    partition_kernel<<<TC, 256, 0, stream>>>(
        s_[0], s_[1], s_[2], s_[3], dsr[0], dsr[1], dsr[2], dsr[3], cnt, bsum, csru);
    finalize_kernel<<<2048, 256, 0, stream>>>(csru, cnt, bsum, rowstart4);
    const int* csr = (const int*)csru;

    // ---- conv layers ----
    int cg = 0, cs = 0;
    for (int l = 0; l < 2; l++) {
        for (int c = 0; c < 4; c++) {
            const u16 *srcHi, *selfHi;
            u16 *outHi;
            if (c == 0)      { srcHi = hgHi[cg]; selfHi = hgHi[cg]; outHi = hgHi[1 - cg]; }
            else if (c == 1) { srcHi = hgHi[cg]; selfHi = hsHi[cs]; outHi = hsHi[1 - cs]; }
            else if (c == 2) { srcHi = hsHi[cs]; selfHi = hsHi[cs]; outHi = hsHi[1 - cs]; }
            else             { srcHi = hsHi[cs]; selfHi = hgHi[cg]; outHi = hgHi[1 - cg]; }
            int do_relu = (l == 0 && c == 3) ? 1 : 0;
            int relu_blocks = (l == 1 && c == 0) ? 512 : 0;
            u32* relu_buf = (l == 1 && c == 0) ? (u32*)hsHi[cs] : (u32*)nullptr;
            conv_fused_kernel<<<2048 + relu_blocks, 256, 0, stream>>>(
                srcHi, selfHi, outHi,
                csr + coff[c], rowstart4 + (size_t)c * RSTRIDE,
                fragbuf + (size_t)(c * 2 + l) * 2048,
                Wl[c] + (size_t)l * (MAXDEG + 1) * H * H,
                Wr[c] + (size_t)l * (MAXDEG + 1) * H * H,
                bl[c] + (size_t)l * (MAXDEG + 1) * H, do_relu, relu_buf);
            if (c == 0 || c == 3) cg ^= 1; else cs ^= 1;
        }
    }

    // ---- pool + MLP ----
    hipMemsetAsync(pooled, 0, (size_t)NB * H * sizeof(float), stream);
    pool_kernel<<<NGROUND / 64, 256, 0, stream>>>(hgHi[cg], batch_idx, pooled);
    mlp_kernel<<<NB, 64, 0, stream>>>(pooled, W1, b1, W2, b2, (float*)d_out);
}